// Round 5
// baseline (305.971 us; speedup 1.0000x reference)
//
#include <hip/hip_runtime.h>

// mPD_loss: B=2048 batches, N=4095 points, POS=4096 cumsum positions.
// out = sum_b mean_j sum_c | cumsum(delta)[b,c,j] |
// delta[j] = (deformed cart step) - (orig cart step); cumsum(a)-cumsum(b)=cumsum(a-b).
//
// R11: R9 structure minus the spills. R10 evidence: WRITE_SIZE 10.3MB +
// FETCH 393MB (vs 238MB app traffic) = px/py/pz[16] register arrays spilled
// to scratch; yet HBM ran at 3.17 TB/s (2.4x prior rounds) and duration was
// exactly fetch/3.17TB/s -> the pipelined small-block structure works, the
// spill bytes ARE the regression. Fix: per-point prefixes go to LDS, which is
// thread-private scratch here (each thread reads back only its own values ->
// no barrier, no cross-thread traffic, zero HBM). pref[3][CH][T] layout is
// lane-contiguous (2 lanes/bank = conflict-free). Register budget: ping-pong
// payload 64 + ~20 misc ~= 85 VGPR, cap 168 via __launch_bounds__(256,3) ->
// no spill. LDS 48KB -> 3 blocks/CU, same ~38% occupancy R10 sustained
// 3.17 TB/s at. Rest = R6 Taylor sincos (angles in [0,2)), wave scan,
// cross-wave LDS table, no atomics.

#define BATCH 2048
#define NPTS  4095
#define POS   4096
#define T     256
#define NW    4       // waves per block
#define CH    16      // points per thread
#define CK    4       // points per chunk

typedef float f4 __attribute__((ext_vector_type(4), aligned(4)));

__device__ __forceinline__ void sincos_poly(float x, float* s, float* c) {
    // x in [0, 2): no argument reduction. Taylor deg-9 (sin) / deg-10 (cos).
    // Max abs err ~5e-5, negligible vs the 2% threshold (absmax was 0.0).
    const float x2 = x * x;
    float ps = 2.7557319e-6f;
    ps = fmaf(ps, x2, -1.9841270e-4f);
    ps = fmaf(ps, x2,  8.3333333e-3f);
    ps = fmaf(ps, x2, -1.6666667e-1f);
    ps = fmaf(ps, x2,  1.0f);
    *s = x * ps;
    float pc = -2.7557319e-7f;
    pc = fmaf(pc, x2,  2.4801587e-5f);
    pc = fmaf(pc, x2, -1.3888889e-3f);
    pc = fmaf(pc, x2,  4.1666667e-2f);
    pc = fmaf(pc, x2, -0.5f);
    pc = fmaf(pc, x2,  1.0f);
    *c = pc;
}

// Compute 4 points' deltas from one chunk payload; running inclusive prefix
// (rx,ry,rz) is stored per-point into LDS (thread-private scratch).
// MASK0: zero k==0 for the last thread (duplicate point).
template<int CBASE, bool MASK0>
__device__ __forceinline__ void comp4(const f4 R3v, const f4 T3v, const f4 P3v,
                                      const f4 R2v, const f4 T2v, const f4 P2v,
                                      const f4 D0v, const f4 D1v,
                                      bool lastT, int t,
                                      float (&pref)[3][CH][T],
                                      float& rx, float& ry, float& rz) {
    #pragma unroll
    for (int k = 0; k < CK; ++k) {
        const float R3  = R3v[k];
        const float Th3 = T3v[k] + D0v[k];
        const float Ph3 = P3v[k] + D1v[k];
        const float R2  = R2v[k];
        const float Th2 = T2v[k];
        const float Ph2 = P2v[k];
        float s3, c3, sp3, cp3, s2, c2, sp2, cp2;
        sincos_poly(Th3, &s3, &c3);
        sincos_poly(Ph3, &sp3, &cp3);
        sincos_poly(Th2, &s2, &c2);
        sincos_poly(Ph2, &sp2, &cp2);
        const float rs3 = R3 * s3;
        const float rs2 = R2 * s2;
        float ddx = rs3 * cp3 - rs2 * cp2;
        float ddy = rs3 * sp3 - rs2 * sp2;
        float ddz = R3 * c3 - R2 * c2;
        if (MASK0 && k == 0 && lastT) { ddx = 0.f; ddy = 0.f; ddz = 0.f; }
        rx += ddx; ry += ddy; rz += ddz;
        pref[0][CBASE + k][t] = rx;
        pref[1][CBASE + k][t] = ry;
        pref[2][CBASE + k][t] = rz;
    }
}

#define LOADP(s, off)                                                        \
    s##R3 = *(const f4*)(r3  + (off));                                       \
    s##T3 = *(const f4*)(th3 + (off));                                       \
    s##P3 = *(const f4*)(ph3 + (off));                                       \
    s##R2 = *(const f4*)(r2  + (off));                                       \
    s##T2 = *(const f4*)(th2 + (off));                                       \
    s##P2 = *(const f4*)(ph2 + (off));                                       \
    s##D0 = *(const f4*)(d0  + (off));                                       \
    s##D1 = *(const f4*)(d1  + (off));                                       \
    asm volatile("" : "+v"(s##R3), "+v"(s##T3), "+v"(s##P3), "+v"(s##R2),    \
                      "+v"(s##T2), "+v"(s##P2), "+v"(s##D0), "+v"(s##D1));

__launch_bounds__(T, 3)
__global__ void mpd_loss_kernel(const float* __restrict__ origin3,
                                const float* __restrict__ sph3,
                                const float* __restrict__ origin2,
                                const float* __restrict__ sph2,
                                const float* __restrict__ def,
                                float* __restrict__ bsum) {
    __shared__ float pref[3][CH][T];   // 48 KB thread-private prefix scratch
    __shared__ float wtot[3][NW];
    __shared__ float wsum[NW];

    const int b    = blockIdx.x;
    const int t    = threadIdx.x;
    const int lane = t & 63;
    const int w    = t >> 6;
    const bool lastT = (t == T - 1);

    const float* r3  = sph3 + (size_t)b * 3 * NPTS;
    const float* th3 = r3 + NPTS;
    const float* ph3 = th3 + NPTS;
    const float* r2  = sph2 + (size_t)b * 3 * NPTS;
    const float* th2 = r2 + NPTS;
    const float* ph2 = th2 + NPTS;
    const float* d0  = def + (size_t)b * 2 * NPTS;   // theta deformation
    const float* d1  = d0 + NPTS;                    // phi deformation

    // Thread t covers points [16t, 16t+16). Thread 255 shifts its window to
    // [4079, 4095) so loads stay in-bounds; k==0 (point 4079, owned by thread
    // 254) is masked in comp4<0,true>.
    const int n0 = lastT ? (NPTS - CH) : (t * CH);

    f4 aR3, aT3, aP3, aR2, aT2, aP2, aD0, aD1;   // ping
    f4 nR3, nT3, nP3, nR2, nT2, nP2, nD0, nD1;   // pong

    float rx = 0.f, ry = 0.f, rz = 0.f;

    // ---- software-pipelined chunks: prefetch c+1, compute c
    LOADP(a, n0)                                  // chunk 0
    LOADP(n, n0 + 4)                              // prefetch chunk 1
    comp4<0, true >(aR3, aT3, aP3, aR2, aT2, aP2, aD0, aD1, lastT, t, pref, rx, ry, rz);
    LOADP(a, n0 + 8)                              // prefetch chunk 2
    comp4<4, false>(nR3, nT3, nP3, nR2, nT2, nP2, nD0, nD1, lastT, t, pref, rx, ry, rz);
    LOADP(n, n0 + 12)                             // prefetch chunk 3
    comp4<8, false>(aR3, aT3, aP3, aR2, aT2, aP2, aD0, aD1, lastT, t, pref, rx, ry, rz);
    comp4<12, false>(nR3, nT3, nP3, nR2, nT2, nP2, nD0, nD1, lastT, t, pref, rx, ry, rz);

    // Thread totals are the last inclusive prefix
    const float tx = rx, ty = ry, tz = rz;

    // ---- Wave inclusive scan over thread totals
    float ix = tx, iy = ty, iz = tz;
    #pragma unroll
    for (int off = 1; off < 64; off <<= 1) {
        const float ux = __shfl_up(ix, off, 64);
        const float uy = __shfl_up(iy, off, 64);
        const float uz = __shfl_up(iz, off, 64);
        if (lane >= off) { ix += ux; iy += uy; iz += uz; }
    }
    if (lane == 63) { wtot[0][w] = ix; wtot[1][w] = iy; wtot[2][w] = iz; }
    __syncthreads();

    // Cross-wave exclusive offsets (broadcast LDS reads)
    float wox = 0.f, woy = 0.f, woz = 0.f;
    #pragma unroll
    for (int ww = 0; ww < NW; ++ww) {
        if (ww < w) { wox += wtot[0][ww]; woy += wtot[1][ww]; woz += wtot[2][ww]; }
    }

    // ---- Origin delta (position 0 of the cumsum)
    const float* o3 = origin3 + (size_t)b * 3;
    const float* o2 = origin2 + (size_t)b * 3;
    const float odx = o3[0] - o2[0];
    const float ody = o3[1] - o2[1];
    const float odz = o3[2] - o2[2];

    // ---- Global offset for this thread's prefixes (exclusive of this thread)
    const float ox = odx + wox + (ix - tx);
    const float oy = ody + woy + (iy - ty);
    const float oz = odz + woz + (iz - tz);

    // ---- Abs accumulation: read own prefixes back from LDS (no barrier
    // needed: same-thread write->read), add offset, accumulate |.|
    float acc = (t == 0) ? (fabsf(odx) + fabsf(ody) + fabsf(odz)) : 0.f;
    #pragma unroll
    for (int k = 0; k < CH; ++k) {
        const bool valid = !(lastT && k == 0);
        if (valid) acc += fabsf(pref[0][k][t] + ox)
                        + fabsf(pref[1][k][t] + oy)
                        + fabsf(pref[2][k][t] + oz);
    }

    // ---- Block reduce, one store per block (no atomics)
    #pragma unroll
    for (int off = 32; off > 0; off >>= 1) acc += __shfl_down(acc, off, 64);
    if (lane == 0) wsum[w] = acc;
    __syncthreads();
    if (t == 0) {
        float s = 0.f;
        #pragma unroll
        for (int i = 0; i < NW; ++i) s += wsum[i];
        bsum[b] = s * (1.0f / POS);
    }
}

__launch_bounds__(256)
__global__ void reduce_kernel(const float* __restrict__ bsum, float* __restrict__ out) {
    const int t = threadIdx.x;
    float acc = 0.f;
    #pragma unroll
    for (int i = 0; i < BATCH / 256; ++i) acc += bsum[t + i * 256];
    #pragma unroll
    for (int off = 32; off > 0; off >>= 1) acc += __shfl_down(acc, off, 64);
    __shared__ float wred[4];
    if ((t & 63) == 0) wred[t >> 6] = acc;
    __syncthreads();
    if (t == 0) out[0] = wred[0] + wred[1] + wred[2] + wred[3];
}

extern "C" void kernel_launch(void* const* d_in, const int* in_sizes, int n_in,
                              void* d_out, int out_size, void* d_ws, size_t ws_size,
                              hipStream_t stream) {
    const float* origin3 = (const float*)d_in[0];
    const float* sph3    = (const float*)d_in[1];
    const float* origin2 = (const float*)d_in[2];
    const float* sph2    = (const float*)d_in[3];
    const float* def     = (const float*)d_in[4];
    float* out  = (float*)d_out;
    float* bsum = (float*)d_ws;   // 2048 floats = 8 KB scratch

    mpd_loss_kernel<<<BATCH, T, 0, stream>>>(origin3, sph3, origin2, sph2, def, bsum);
    reduce_kernel<<<1, 256, 0, stream>>>(bsum, out);
}

// Round 6
// 266.654 us; speedup vs baseline: 1.1474x; 1.1474x over previous
//
#include <hip/hip_runtime.h>

// mPD_loss: B=2048 batches, N=4095 points, POS=4096 cumsum positions.
// out = sum_b mean_j sum_c | cumsum(delta)[b,c,j] |
// delta[j] = (deformed cart step) - (orig cart step); cumsum(a)-cumsum(b)=cumsum(a-b).
//
// R12: kill the over-fetch. R11 evidence: WRITE_SIZE 10.3MB->85KB (spills
// fixed) but FETCH_SIZE 442MB = 1.86x the 238MB app working set, duration
// exactly fetch/3.27TB/s -> purely HBM-fetch-bound on wasted bytes. Cause:
// thread-contiguous CH=16 chunked f4 loads give a 64B lane stride (16B used
// per 64B line per instruction); chunk-to-chunk partial-line reuse dies in
// the 4MB L2 under ~96 resident blocks/XCD -> ~1.9x re-fetch + L3 thrash.
// Fix: wave-dense chunk layout. Each wave owns 1024 consecutive points as
// 4 chunks of 256; lane l takes points [c*256+l*4, +4) -> every load is
// 64x16B CONTIGUOUS (dense, like R7) while keeping R9's pipelining (prefetch
// chunk c+1 before computing chunk c). Point order now needs one 64-lane
// scan per chunk + chunk-total chaining (~300 extra VALU/DS ops vs a 10%-
// busy VALU pipe - cheap). LDS prefixes stored pre-adjusted with all
// wave-internal offsets; pass 2 adds only cross-wave + origin offset.
// Rest = R6 Taylor sincos (angles in [0,2)), LDS cross-wave table, no atomics.

#define BATCH 2048
#define NPTS  4095
#define POS   4096
#define T     256
#define NW    4       // waves per block
#define CH    16      // points per thread (4 chunks x 4)
#define CK    4       // points per chunk per lane

typedef float f4 __attribute__((ext_vector_type(4), aligned(4)));

__device__ __forceinline__ void sincos_poly(float x, float* s, float* c) {
    // x in [0, 2): no argument reduction. Taylor deg-9 (sin) / deg-10 (cos).
    // Max abs err ~5e-5, negligible vs the 2% threshold (absmax was 0.0).
    const float x2 = x * x;
    float ps = 2.7557319e-6f;
    ps = fmaf(ps, x2, -1.9841270e-4f);
    ps = fmaf(ps, x2,  8.3333333e-3f);
    ps = fmaf(ps, x2, -1.6666667e-1f);
    ps = fmaf(ps, x2,  1.0f);
    *s = x * ps;
    float pc = -2.7557319e-7f;
    pc = fmaf(pc, x2,  2.4801587e-5f);
    pc = fmaf(pc, x2, -1.3888889e-3f);
    pc = fmaf(pc, x2,  4.1666667e-2f);
    pc = fmaf(pc, x2, -0.5f);
    pc = fmaf(pc, x2,  1.0f);
    *c = pc;
}

// Process one 256-point chunk of this wave: compute 4 deltas/lane, in-lane
// inclusive prefix, 64-lane wave scan, store wave-adjusted prefixes to LDS,
// advance the wave-uniform chunk base (cbx,cby,cbz).
// EDGE: last lane of the last wave's last chunk has a shifted window; its
// k==0 is a duplicate of lane 62's k==3 and must be masked from the sums.
template<int CHUNK, bool EDGE>
__device__ __forceinline__ void do_chunk(const f4 R3v, const f4 T3v, const f4 P3v,
                                         const f4 R2v, const f4 T2v, const f4 P2v,
                                         const f4 D0v, const f4 D1v,
                                         bool lastT, int lane, int t,
                                         float (&pref)[3][CH][T],
                                         float& cbx, float& cby, float& cbz) {
    float px[CK], py[CK], pz[CK];
    float rx = 0.f, ry = 0.f, rz = 0.f;
    #pragma unroll
    for (int k = 0; k < CK; ++k) {
        const float R3  = R3v[k];
        const float Th3 = T3v[k] + D0v[k];
        const float Ph3 = P3v[k] + D1v[k];
        const float R2  = R2v[k];
        const float Th2 = T2v[k];
        const float Ph2 = P2v[k];
        float s3, c3, sp3, cp3, s2, c2, sp2, cp2;
        sincos_poly(Th3, &s3, &c3);
        sincos_poly(Ph3, &sp3, &cp3);
        sincos_poly(Th2, &s2, &c2);
        sincos_poly(Ph2, &sp2, &cp2);
        const float rs3 = R3 * s3;
        const float rs2 = R2 * s2;
        float ddx = rs3 * cp3 - rs2 * cp2;
        float ddy = rs3 * sp3 - rs2 * sp2;
        float ddz = R3 * c3 - R2 * c2;
        if (EDGE && k == 0 && lastT) { ddx = 0.f; ddy = 0.f; ddz = 0.f; }
        rx += ddx; ry += ddy; rz += ddz;
        px[k] = rx; py[k] = ry; pz[k] = rz;
    }
    // Wave inclusive scan over lane chunk-totals (rx,ry,rz)
    float ix = rx, iy = ry, iz = rz;
    #pragma unroll
    for (int off = 1; off < 64; off <<= 1) {
        const float ux = __shfl_up(ix, off, 64);
        const float uy = __shfl_up(iy, off, 64);
        const float uz = __shfl_up(iz, off, 64);
        if (lane >= off) { ix += ux; iy += uy; iz += uz; }
    }
    // Lane-exclusive offset within wave (incl. earlier chunks of this wave)
    const float ex = ix - rx + cbx;
    const float ey = iy - ry + cby;
    const float ez = iz - rz + cbz;
    #pragma unroll
    for (int k = 0; k < CK; ++k) {
        pref[0][CHUNK * CK + k][t] = px[k] + ex;
        pref[1][CHUNK * CK + k][t] = py[k] + ey;
        pref[2][CHUNK * CK + k][t] = pz[k] + ez;
    }
    // Advance wave-uniform base by this chunk's total (broadcast from lane 63)
    cbx += __shfl(ix, 63, 64);
    cby += __shfl(iy, 63, 64);
    cbz += __shfl(iz, 63, 64);
}

#define LOADP(s, off)                                                        \
    s##R3 = *(const f4*)(r3  + (off));                                       \
    s##T3 = *(const f4*)(th3 + (off));                                       \
    s##P3 = *(const f4*)(ph3 + (off));                                       \
    s##R2 = *(const f4*)(r2  + (off));                                       \
    s##T2 = *(const f4*)(th2 + (off));                                       \
    s##P2 = *(const f4*)(ph2 + (off));                                       \
    s##D0 = *(const f4*)(d0  + (off));                                       \
    s##D1 = *(const f4*)(d1  + (off));                                       \
    asm volatile("" : "+v"(s##R3), "+v"(s##T3), "+v"(s##P3), "+v"(s##R2),    \
                      "+v"(s##T2), "+v"(s##P2), "+v"(s##D0), "+v"(s##D1));

__launch_bounds__(T, 3)
__global__ void mpd_loss_kernel(const float* __restrict__ origin3,
                                const float* __restrict__ sph3,
                                const float* __restrict__ origin2,
                                const float* __restrict__ sph2,
                                const float* __restrict__ def,
                                float* __restrict__ bsum) {
    __shared__ float pref[3][CH][T];   // 48 KB thread-private prefix scratch
    __shared__ float wtot[3][NW];
    __shared__ float wsum[NW];

    const int b    = blockIdx.x;
    const int t    = threadIdx.x;
    const int lane = t & 63;
    const int w    = t >> 6;
    const bool lastT = (t == T - 1);   // wave 3, lane 63

    const float* r3  = sph3 + (size_t)b * 3 * NPTS;
    const float* th3 = r3 + NPTS;
    const float* ph3 = th3 + NPTS;
    const float* r2  = sph2 + (size_t)b * 3 * NPTS;
    const float* th2 = r2 + NPTS;
    const float* ph2 = th2 + NPTS;
    const float* d0  = def + (size_t)b * 2 * NPTS;   // theta deformation
    const float* d1  = d0 + NPTS;                    // phi deformation

    // Wave w owns points [w*1024, (w+1)*1024) in 4 chunks of 256; lane l of
    // chunk c covers [w*1024 + c*256 + 4l, +4). Loads are 64x16B contiguous.
    // Last lane of wave 3, chunk 3 would need [4092,4096); shift to
    // [4091,4095) and mask k==0 (dup of lane 62's k==3) inside do_chunk.
    const int wbase = w * 1024;
    const int l4    = lane * 4;
    const int off0  = wbase + l4;
    const int off1  = wbase + 256 + l4;
    const int off2  = wbase + 512 + l4;
    const int off3  = lastT ? (NPTS - CK) : (wbase + 768 + l4);

    f4 aR3, aT3, aP3, aR2, aT2, aP2, aD0, aD1;   // ping
    f4 nR3, nT3, nP3, nR2, nT2, nP2, nD0, nD1;   // pong

    float cbx = 0.f, cby = 0.f, cbz = 0.f;       // wave-uniform chunk base

    // ---- software-pipelined chunks: prefetch c+1, compute c
    LOADP(a, off0)                                // chunk 0
    LOADP(n, off1)                                // prefetch chunk 1
    do_chunk<0, false>(aR3, aT3, aP3, aR2, aT2, aP2, aD0, aD1, lastT, lane, t, pref, cbx, cby, cbz);
    LOADP(a, off2)                                // prefetch chunk 2
    do_chunk<1, false>(nR3, nT3, nP3, nR2, nT2, nP2, nD0, nD1, lastT, lane, t, pref, cbx, cby, cbz);
    LOADP(n, off3)                                // prefetch chunk 3
    do_chunk<2, false>(aR3, aT3, aP3, aR2, aT2, aP2, aD0, aD1, lastT, lane, t, pref, cbx, cby, cbz);
    do_chunk<3, true >(nR3, nT3, nP3, nR2, nT2, nP2, nD0, nD1, lastT, lane, t, pref, cbx, cby, cbz);

    // cbx/cby/cbz now = this wave's total delta (wave-uniform)
    if (lane == 0) { wtot[0][w] = cbx; wtot[1][w] = cby; wtot[2][w] = cbz; }
    __syncthreads();

    // Cross-wave exclusive offsets (broadcast LDS reads)
    float wox = 0.f, woy = 0.f, woz = 0.f;
    #pragma unroll
    for (int ww = 0; ww < NW; ++ww) {
        if (ww < w) { wox += wtot[0][ww]; woy += wtot[1][ww]; woz += wtot[2][ww]; }
    }

    // ---- Origin delta (position 0 of the cumsum)
    const float* o3 = origin3 + (size_t)b * 3;
    const float* o2 = origin2 + (size_t)b * 3;
    const float odx = o3[0] - o2[0];
    const float ody = o3[1] - o2[1];
    const float odz = o3[2] - o2[2];

    // ---- Final offset for this thread's stored prefixes
    const float ox = odx + wox;
    const float oy = ody + woy;
    const float oz = odz + woz;

    // ---- Abs accumulation: read own prefixes back from LDS
    float acc = (t == 0) ? (fabsf(odx) + fabsf(ody) + fabsf(odz)) : 0.f;
    #pragma unroll
    for (int k = 0; k < CH; ++k) {
        const bool valid = !(lastT && k == 12);   // chunk 3, k==0 dup
        if (valid) acc += fabsf(pref[0][k][t] + ox)
                        + fabsf(pref[1][k][t] + oy)
                        + fabsf(pref[2][k][t] + oz);
    }

    // ---- Block reduce, one store per block (no atomics)
    #pragma unroll
    for (int off = 32; off > 0; off >>= 1) acc += __shfl_down(acc, off, 64);
    if (lane == 0) wsum[w] = acc;
    __syncthreads();
    if (t == 0) {
        float s = 0.f;
        #pragma unroll
        for (int i = 0; i < NW; ++i) s += wsum[i];
        bsum[b] = s * (1.0f / POS);
    }
}

__launch_bounds__(256)
__global__ void reduce_kernel(const float* __restrict__ bsum, float* __restrict__ out) {
    const int t = threadIdx.x;
    float acc = 0.f;
    #pragma unroll
    for (int i = 0; i < BATCH / 256; ++i) acc += bsum[t + i * 256];
    #pragma unroll
    for (int off = 32; off > 0; off >>= 1) acc += __shfl_down(acc, off, 64);
    __shared__ float wred[4];
    if ((t & 63) == 0) wred[t >> 6] = acc;
    __syncthreads();
    if (t == 0) out[0] = wred[0] + wred[1] + wred[2] + wred[3];
}

extern "C" void kernel_launch(void* const* d_in, const int* in_sizes, int n_in,
                              void* d_out, int out_size, void* d_ws, size_t ws_size,
                              hipStream_t stream) {
    const float* origin3 = (const float*)d_in[0];
    const float* sph3    = (const float*)d_in[1];
    const float* origin2 = (const float*)d_in[2];
    const float* sph2    = (const float*)d_in[3];
    const float* def     = (const float*)d_in[4];
    float* out  = (float*)d_out;
    float* bsum = (float*)d_ws;   // 2048 floats = 8 KB scratch

    mpd_loss_kernel<<<BATCH, T, 0, stream>>>(origin3, sph3, origin2, sph2, def, bsum);
    reduce_kernel<<<1, 256, 0, stream>>>(bsum, out);
}

// Round 7
// 265.936 us; speedup vs baseline: 1.1505x; 1.0027x over previous
//
#include <hip/hip_runtime.h>

// mPD_loss: B=2048 batches, N=4095 points, POS=4096 cumsum positions.
// out = sum_b mean_j sum_c | cumsum(delta)[b,c,j] |
// delta[j] = (deformed cart step) - (orig cart step); cumsum(a)-cumsum(b)=cumsum(a-b).
//
// R13: R6 base (T=512, CH=8, register deltas, 97us best) + TRUE no-drain MLP.
// Bug found in R8-R12: asm volatile("":"+v"(x)) READS the loaded regs ->
// compiler inserts s_waitcnt vmcnt(0) BEFORE the asm -> every "prefetch"
// fully drained at issue; the pipeline never pipelined. Correct idiom:
// asm volatile("" ::: "memory") AFTER the loads — pins all 16 dwordx4 issues
// above it (loads can't cross a potential-write barrier) but reads no regs,
// so no forced wait; the compiler then places incremental vmcnt(N) at first
// use. All 16KB/wave stay in flight under the compute; ~20 waves/CU ->
// ~320KB/CU outstanding vs R6's ~40KB (its VGPR=32 proves load dribbling).
// EXT arrays replaced by inline per-k selects to cap liveness (~95 VGPR).
// Rest = R6: Taylor sincos (angles in [0,2)), wave scan, cross-wave LDS
// table, no atomics. Tail: thread 511's 2nd load shifts back 1; k==7 masked.

#define BATCH 2048
#define NPTS  4095
#define POS   4096
#define T     512
#define NW    8       // waves per block
#define CH    8       // contiguous points per thread

typedef float f4 __attribute__((ext_vector_type(4), aligned(4)));

__device__ __forceinline__ void sincos_poly(float x, float* s, float* c) {
    // x in [0, 2): no argument reduction. Taylor deg-9 (sin) / deg-10 (cos).
    // Max abs err ~5e-5, negligible vs the 2% threshold (absmax was 0.0).
    const float x2 = x * x;
    float ps = 2.7557319e-6f;
    ps = fmaf(ps, x2, -1.9841270e-4f);
    ps = fmaf(ps, x2,  8.3333333e-3f);
    ps = fmaf(ps, x2, -1.6666667e-1f);
    ps = fmaf(ps, x2,  1.0f);
    *s = x * ps;
    float pc = -2.7557319e-7f;
    pc = fmaf(pc, x2,  2.4801587e-5f);
    pc = fmaf(pc, x2, -1.3888889e-3f);
    pc = fmaf(pc, x2,  4.1666667e-2f);
    pc = fmaf(pc, x2, -0.5f);
    pc = fmaf(pc, x2,  1.0f);
    *c = pc;
}

// Element k of the thread's 8-point window, from the two f4 halves.
// k<4 -> A[k]; k>=4 -> B[k-4], except lastT (shifted window) -> B[k-3].
// All selects are compile-time except the lastT cndmask.
#define ELT(A, Bv, k) ((k) < 4 ? (A)[(k)] : \
                       ((k) == 7 ? (Bv)[3] : (lastT ? (Bv)[(k)-3] : (Bv)[(k)-4])))

__launch_bounds__(T, 4)
__global__ void mpd_loss_kernel(const float* __restrict__ origin3,
                                const float* __restrict__ sph3,
                                const float* __restrict__ origin2,
                                const float* __restrict__ sph2,
                                const float* __restrict__ def,
                                float* __restrict__ bsum) {
    __shared__ float wtot[3][NW];
    __shared__ float wsum[NW];

    const int b    = blockIdx.x;
    const int t    = threadIdx.x;
    const int lane = t & 63;
    const int w    = t >> 6;
    const bool lastT = (t == T - 1);

    const float* r3  = sph3 + (size_t)b * 3 * NPTS;
    const float* th3 = r3 + NPTS;
    const float* ph3 = th3 + NPTS;
    const float* r2  = sph2 + (size_t)b * 3 * NPTS;
    const float* th2 = r2 + NPTS;
    const float* ph2 = th2 + NPTS;
    const float* d0  = def + (size_t)b * 2 * NPTS;   // theta deformation
    const float* d1  = d0 + NPTS;                    // phi deformation

    // Thread t covers points [8t, 8t+8); thread 511's 2nd half shifts back 1
    // to stay in-bounds (k==7 duplicate masked below).
    const int n0 = t * CH;
    const int n1 = lastT ? (n0 + 3) : (n0 + 4);

    // ---- 16 independent dwordx4 loads, ALL issued before any wait.
    const f4 aR3 = *(const f4*)(r3  + n0);  const f4 bR3 = *(const f4*)(r3  + n1);
    const f4 aT3 = *(const f4*)(th3 + n0);  const f4 bT3 = *(const f4*)(th3 + n1);
    const f4 aP3 = *(const f4*)(ph3 + n0);  const f4 bP3 = *(const f4*)(ph3 + n1);
    const f4 aR2 = *(const f4*)(r2  + n0);  const f4 bR2 = *(const f4*)(r2  + n1);
    const f4 aT2 = *(const f4*)(th2 + n0);  const f4 bT2 = *(const f4*)(th2 + n1);
    const f4 aP2 = *(const f4*)(ph2 + n0);  const f4 bP2 = *(const f4*)(ph2 + n1);
    const f4 aD0 = *(const f4*)(d0  + n0);  const f4 bD0 = *(const f4*)(d0  + n1);
    const f4 aD1 = *(const f4*)(d1  + n0);  const f4 bD1 = *(const f4*)(d1  + n1);

    // Scheduling barrier: loads may not sink below this point (reads can't
    // cross a potential write), but NO registers are read here -> no forced
    // s_waitcnt. Compiler places incremental vmcnt(N) at first consumption.
    asm volatile("" ::: "memory");

    // ---- Deltas in registers + thread totals
    float dx[CH], dy[CH], dz[CH];
    float tx = 0.f, ty = 0.f, tz = 0.f;
    #pragma unroll
    for (int k = 0; k < CH; ++k) {
        const bool valid = (k < 7) || !lastT;   // n = 8t+k < NPTS
        const float R3  = ELT(aR3, bR3, k);
        const float Th3 = ELT(aT3, bT3, k) + ELT(aD0, bD0, k);
        const float Ph3 = ELT(aP3, bP3, k) + ELT(aD1, bD1, k);
        const float R2  = ELT(aR2, bR2, k);
        const float Th2 = ELT(aT2, bT2, k);
        const float Ph2 = ELT(aP2, bP2, k);
        float s3, c3, sp3, cp3, s2, c2, sp2, cp2;
        sincos_poly(Th3, &s3, &c3);
        sincos_poly(Ph3, &sp3, &cp3);
        sincos_poly(Th2, &s2, &c2);
        sincos_poly(Ph2, &sp2, &cp2);
        const float rs3 = R3 * s3;
        const float rs2 = R2 * s2;
        float ddx = rs3 * cp3 - rs2 * cp2;
        float ddy = rs3 * sp3 - rs2 * sp2;
        float ddz = R3 * c3 - R2 * c2;
        if (!valid) { ddx = 0.f; ddy = 0.f; ddz = 0.f; }
        dx[k] = ddx; dy[k] = ddy; dz[k] = ddz;
        tx += ddx; ty += ddy; tz += ddz;
    }

    // ---- Wave inclusive scan over thread totals
    float ix = tx, iy = ty, iz = tz;
    #pragma unroll
    for (int off = 1; off < 64; off <<= 1) {
        const float ux = __shfl_up(ix, off, 64);
        const float uy = __shfl_up(iy, off, 64);
        const float uz = __shfl_up(iz, off, 64);
        if (lane >= off) { ix += ux; iy += uy; iz += uz; }
    }
    if (lane == 63) { wtot[0][w] = ix; wtot[1][w] = iy; wtot[2][w] = iz; }
    __syncthreads();

    // Cross-wave exclusive offsets (broadcast LDS reads)
    float wox = 0.f, woy = 0.f, woz = 0.f;
    #pragma unroll
    for (int ww = 0; ww < NW; ++ww) {
        if (ww < w) { wox += wtot[0][ww]; woy += wtot[1][ww]; woz += wtot[2][ww]; }
    }

    // ---- Origin delta (position 0 of the cumsum)
    const float* o3 = origin3 + (size_t)b * 3;
    const float* o2 = origin2 + (size_t)b * 3;
    const float odx = o3[0] - o2[0];
    const float ody = o3[1] - o2[1];
    const float odz = o3[2] - o2[2];

    // ---- Running prefix + abs accumulation
    float px = odx + wox + (ix - tx);
    float py = ody + woy + (iy - ty);
    float pz = odz + woz + (iz - tz);
    float acc = (t == 0) ? (fabsf(odx) + fabsf(ody) + fabsf(odz)) : 0.f;
    #pragma unroll
    for (int k = 0; k < CH; ++k) {
        const bool valid = (k < 7) || !lastT;
        px += dx[k]; py += dy[k]; pz += dz[k];
        if (valid) acc += fabsf(px) + fabsf(py) + fabsf(pz);
    }

    // ---- Block reduce, one store per block (no atomics)
    #pragma unroll
    for (int off = 32; off > 0; off >>= 1) acc += __shfl_down(acc, off, 64);
    if (lane == 0) wsum[w] = acc;
    __syncthreads();
    if (t == 0) {
        float s = 0.f;
        #pragma unroll
        for (int i = 0; i < NW; ++i) s += wsum[i];
        bsum[b] = s * (1.0f / POS);
    }
}

__launch_bounds__(256)
__global__ void reduce_kernel(const float* __restrict__ bsum, float* __restrict__ out) {
    const int t = threadIdx.x;
    float acc = 0.f;
    #pragma unroll
    for (int i = 0; i < BATCH / 256; ++i) acc += bsum[t + i * 256];
    #pragma unroll
    for (int off = 32; off > 0; off >>= 1) acc += __shfl_down(acc, off, 64);
    __shared__ float wred[4];
    if ((t & 63) == 0) wred[t >> 6] = acc;
    __syncthreads();
    if (t == 0) out[0] = wred[0] + wred[1] + wred[2] + wred[3];
}

extern "C" void kernel_launch(void* const* d_in, const int* in_sizes, int n_in,
                              void* d_out, int out_size, void* d_ws, size_t ws_size,
                              hipStream_t stream) {
    const float* origin3 = (const float*)d_in[0];
    const float* sph3    = (const float*)d_in[1];
    const float* origin2 = (const float*)d_in[2];
    const float* sph2    = (const float*)d_in[3];
    const float* def     = (const float*)d_in[4];
    float* out  = (float*)d_out;
    float* bsum = (float*)d_ws;   // 2048 floats = 8 KB scratch

    mpd_loss_kernel<<<BATCH, T, 0, stream>>>(origin3, sph3, origin2, sph2, def, bsum);
    reduce_kernel<<<1, 256, 0, stream>>>(bsum, out);
}